// Round 5
// baseline (52.287 us; speedup 1.0000x reference)
//
#include <hip/hip_runtime.h>

// Sliding-window min (window=64) over rows of T=8192 fp32.
// Gil-Werman, 4 elems/lane, segment = 64 elems = one 16-lane DPP row.
//
// R5 changes vs R4:
//  - GRP_ELEMS 512 -> 1024 (halo read overhead 12.5% -> 6.25%), 2 rows per
//    block -> 2048 blocks = exactly 8 resident blocks/CU (32 waves, single
//    dispatch round), prologue count halved.
//  - Rolling prefetch window of 6 (static indices under full unroll) for
//    ~6KB in flight per wave while keeping VGPR low.

constexpr int T = 8192;
constexpr float INIT_VAL = 9999.0f;
constexpr int ROWS_PER_BLOCK = 2;
constexpr int BLOCK_ELEMS = T * ROWS_PER_BLOCK;     // 16384
constexpr int GRP_ELEMS = 1024;                     // per 16-lane group
constexpr int ITERS = GRP_ELEMS / 64;               // 16 segments per group
constexpr int PF = 6;                               // prefetch window

typedef float f4v __attribute__((ext_vector_type(4)));

// DPP move: dst = row-relative shift of src; invalid lanes get `old`.
// row_shr:N = 0x110|N (lane i reads lane i-N), row_shl:N = 0x100|N.
template <int CTRL>
__device__ __forceinline__ float dppmov(float old, float src) {
    return __builtin_bit_cast(
        float, __builtin_amdgcn_update_dpp(
                   __builtin_bit_cast(int, old), __builtin_bit_cast(int, src),
                   CTRL, 0xF, 0xF, false));
}

__global__ __launch_bounds__(256)
void tlalw_kernel(const float* __restrict__ x, float* __restrict__ y) {
    const int tid = threadIdx.x;
    const int g = tid & 15;                  // position within DPP row
    const int gid = tid >> 4;                // group 0..15 within block
    const long long base = (long long)blockIdx.x * BLOCK_ELEMS
                           + (long long)gid * GRP_ELEMS;
    const float* __restrict__ xg = x + base;
    float* __restrict__ yg = y + base;

    // carry_j : Sshift_j of the preceding segment, in-lane.
    float carry0, carry1, carry2, carry3;

    // Prologue: halo segment [-64, 0) relative to this group's range.
    // Groups whose range starts a row (gid % 8 == 0) pad with INIT_VAL.
    {
        f4v v;
        if ((gid & 7) != 0) v = *(const f4v*)(xg - 64 + 4 * g);
        else v = (f4v){INIT_VAL, INIT_VAL, INIT_VAL, INIT_VAL};
        float s3 = v.w, s2 = fminf(v.z, s3), s1 = fminf(v.y, s2), s0 = fminf(v.x, s1);
        float eS = dppmov<0x101>(INIT_VAL, s0);
        eS = fminf(eS, dppmov<0x101>(INIT_VAL, eS));
        eS = fminf(eS, dppmov<0x102>(INIT_VAL, eS));
        eS = fminf(eS, dppmov<0x104>(INIT_VAL, eS));
        eS = fminf(eS, dppmov<0x108>(INIT_VAL, eS));
        float S0 = fminf(eS, s0);
        carry0 = fminf(eS, s1);
        carry1 = fminf(eS, s2);
        carry2 = fminf(eS, s3);
        carry3 = dppmov<0x101>(INIT_VAL, S0);
    }

    // Rolling prefetch window (indices static under full unroll).
    f4v vb[PF];
    #pragma unroll
    for (int i = 0; i < PF; ++i)
        vb[i] = *(const f4v*)(xg + i * 64 + 4 * g);

    #pragma unroll
    for (int it = 0; it < ITERS; ++it) {
        const f4v v = vb[it % PF];
        if (it + PF < ITERS)
            vb[it % PF] = *(const f4v*)(xg + (it + PF) * 64 + 4 * g);

        float p0 = v.x, p1 = fminf(p0, v.y), p2 = fminf(p1, v.z), p3 = fminf(p2, v.w);
        float s3 = v.w, s2 = fminf(v.z, s3), s1 = fminf(v.y, s2), s0 = fminf(v.x, s1);

        // exclusive prefix-min of lane aggregate (p3) within the 16-lane row
        float eP = dppmov<0x111>(INIT_VAL, p3);
        eP = fminf(eP, dppmov<0x111>(INIT_VAL, eP));
        eP = fminf(eP, dppmov<0x112>(INIT_VAL, eP));
        eP = fminf(eP, dppmov<0x114>(INIT_VAL, eP));
        eP = fminf(eP, dppmov<0x118>(INIT_VAL, eP));

        // exclusive suffix-min of lane aggregate (s0) within the row
        float eS = dppmov<0x101>(INIT_VAL, s0);
        eS = fminf(eS, dppmov<0x101>(INIT_VAL, eS));
        eS = fminf(eS, dppmov<0x102>(INIT_VAL, eS));
        eS = fminf(eS, dppmov<0x104>(INIT_VAL, eS));
        eS = fminf(eS, dppmov<0x108>(INIT_VAL, eS));

        f4v o;
        o.x = fminf(fminf(eP, p0), carry0);
        o.y = fminf(fminf(eP, p1), carry1);
        o.z = fminf(fminf(eP, p2), carry2);
        o.w = fminf(fminf(eP, p3), carry3);
        __builtin_nontemporal_store(o, (f4v*)(yg + it * 64 + 4 * g));

        float S0 = fminf(eS, s0);
        carry0 = fminf(eS, s1);
        carry1 = fminf(eS, s2);
        carry2 = fminf(eS, s3);
        carry3 = dppmov<0x101>(INIT_VAL, S0);
    }
}

extern "C" void kernel_launch(void* const* d_in, const int* in_sizes, int n_in,
                              void* d_out, int out_size, void* d_ws, size_t ws_size,
                              hipStream_t stream) {
    const float* x = (const float*)d_in[0];
    float* y = (float*)d_out;
    const int B = in_sizes[0] / T;                    // 4096 rows
    tlalw_kernel<<<B / ROWS_PER_BLOCK, 256, 0, stream>>>(x, y);
}

// Round 6
// 45.384 us; speedup vs baseline: 1.1521x; 1.1521x over previous
//
#include <hip/hip_runtime.h>

// Sliding-window min (window=64) over rows of T=8192 fp32, Gil-Werman with
// 4 elements/lane. Segment of 64 elements = 16 lanes x float4. Per iteration
// (256 elems/wave): lane-local prefix/suffix mins, exclusive prefix/suffix
// scans of lane aggregates within 16-lane groups (5+5 shuffles), segment
// shift (1 shuffle), rotate-by-16 to deliver prev-segment suffixes.
//
// BEST-KNOWN configuration (R3, 45.5us = ~97% of the 6.29 TB/s streaming
// roofline on 268MB r+w traffic). R4 (pure-DPP, zero DS) and R5 (bigger
// groups, fewer blocks) were neutral/regressions — memory-system bound.

constexpr int T = 8192;
constexpr float INIT_VAL = 9999.0f;
constexpr int WAVE = 64;
constexpr int WAVES_PER_BLOCK = 4;
constexpr int CHUNK = WAVE * 4;                         // 256 elems/iter/wave
constexpr int ITERS = T / (WAVES_PER_BLOCK * CHUNK);    // 8

typedef float f4v __attribute__((ext_vector_type(4)));

__global__ __launch_bounds__(WAVE * WAVES_PER_BLOCK)
void tlalw_kernel(const float* __restrict__ x, float* __restrict__ y) {
    const int lane = threadIdx.x & 63;
    const int g = lane & 15;                 // position within 16-lane group
    const int wv = threadIdx.x >> 6;
    const long long rowBase = (long long)blockIdx.x * T;
    const float* __restrict__ xr = x + rowBase;
    float* __restrict__ yr = y + rowBase;
    const int tbase = wv * (ITERS * CHUNK);
    const int rotIdx = (lane + 48) & 63;     // lane-16 mod 64

    // carry_j (valid in lanes 0..15): Sshift_j of the segment preceding this
    // iteration's segment 0.
    float carry0, carry1, carry2, carry3;

    // Prologue: halo segment [tbase-64, tbase). All four 16-lane groups
    // compute it redundantly; lanes 0..15 hold the carry.
    {
        f4v v;
        const int th = tbase - 64 + 4 * g;
        if (th >= 0) v = *(const f4v*)(xr + th);
        else v = (f4v){INIT_VAL, INIT_VAL, INIT_VAL, INIT_VAL};
        float s3 = v.w, s2 = fminf(v.z, s3), s1 = fminf(v.y, s2), s0 = fminf(v.x, s1);
        float m = s0;
        float eS = __shfl_down(m, 1, 16); eS = (g == 15) ? INIT_VAL : eS;
        eS = fminf(eS, __shfl_down(eS, 1, 16));
        eS = fminf(eS, __shfl_down(eS, 2, 16));
        eS = fminf(eS, __shfl_down(eS, 4, 16));
        eS = fminf(eS, __shfl_down(eS, 8, 16));
        float S0 = fminf(eS, s0), S1 = fminf(eS, s1), S2 = fminf(eS, s2), S3 = fminf(eS, s3);
        float nS0 = __shfl_down(S0, 1, 16);
        carry0 = S1; carry1 = S2; carry2 = S3;
        carry3 = (g == 15) ? INIT_VAL : nS0;
    }

    #pragma unroll
    for (int it = 0; it < ITERS; ++it) {
        const int t0 = tbase + it * CHUNK + 4 * lane;
        f4v v = *(const f4v*)(xr + t0);

        float p0 = v.x, p1 = fminf(p0, v.y), p2 = fminf(p1, v.z), p3 = fminf(p2, v.w);
        float s3 = v.w, s2 = fminf(v.z, s3), s1 = fminf(v.y, s2), s0 = fminf(v.x, s1);
        float m = p3;

        // exclusive prefix-min scan of m within 16-lane group
        // (__shfl_up clamps to self out-of-range; fminf idempotent)
        float eP = __shfl_up(m, 1, 16); eP = (g == 0) ? INIT_VAL : eP;
        eP = fminf(eP, __shfl_up(eP, 1, 16));
        eP = fminf(eP, __shfl_up(eP, 2, 16));
        eP = fminf(eP, __shfl_up(eP, 4, 16));
        eP = fminf(eP, __shfl_up(eP, 8, 16));

        // exclusive suffix-min scan of m within 16-lane group
        float eS = __shfl_down(m, 1, 16); eS = (g == 15) ? INIT_VAL : eS;
        eS = fminf(eS, __shfl_down(eS, 1, 16));
        eS = fminf(eS, __shfl_down(eS, 2, 16));
        eS = fminf(eS, __shfl_down(eS, 4, 16));
        eS = fminf(eS, __shfl_down(eS, 8, 16));

        float P0 = fminf(eP, p0), P1 = fminf(eP, p1), P2 = fminf(eP, p2), P3 = fminf(eP, p3);
        float S0 = fminf(eS, s0), S1 = fminf(eS, s1), S2 = fminf(eS, s2), S3 = fminf(eS, s3);

        // Sshift_j = S[r+1] within segment; r+1==64 -> INIT
        float nS0 = __shfl_down(S0, 1, 16);
        float Sh0 = S1, Sh1 = S2, Sh2 = S3;
        float Sh3 = (g == 15) ? INIT_VAL : nS0;

        // rotate by 16 lanes: prev segment's Sshift (lanes>=16), and for
        // lanes 0..15 this delivers segment 3's Sshift = next iter's carry
        float r0 = __shfl(Sh0, rotIdx);
        float r1 = __shfl(Sh1, rotIdx);
        float r2 = __shfl(Sh2, rotIdx);
        float r3 = __shfl(Sh3, rotIdx);

        float pv0 = (lane >= 16) ? r0 : carry0;
        float pv1 = (lane >= 16) ? r1 : carry1;
        float pv2 = (lane >= 16) ? r2 : carry2;
        float pv3 = (lane >= 16) ? r3 : carry3;

        f4v o;
        o.x = fminf(P0, pv0);
        o.y = fminf(P1, pv1);
        o.z = fminf(P2, pv2);
        o.w = fminf(P3, pv3);
        __builtin_nontemporal_store(o, (f4v*)(yr + t0));

        carry0 = r0; carry1 = r1; carry2 = r2; carry3 = r3;
    }
}

extern "C" void kernel_launch(void* const* d_in, const int* in_sizes, int n_in,
                              void* d_out, int out_size, void* d_ws, size_t ws_size,
                              hipStream_t stream) {
    const float* x = (const float*)d_in[0];
    float* y = (float*)d_out;
    const int B = in_sizes[0] / T; // 4096 rows
    tlalw_kernel<<<B, WAVE * WAVES_PER_BLOCK, 0, stream>>>(x, y);
}